// Round 3
// baseline (302.387 us; speedup 1.0000x reference)
//
#include <hip/hip_runtime.h>

#define DIM 64
#define NHEADS 8
#define NPOS 2048
#define PADW 3

typedef float f32x4 __attribute__((ext_vector_type(4)));

// Taylor coefficients 1/j!
#define C1 1.0f
#define C2 0.5f
#define C3 (1.0f / 6.0f)
#define C4 (1.0f / 24.0f)
#define C5 (1.0f / 120.0f)
#define C6 (1.0f / 720.0f)
#define C7 (1.0f / 5040.0f)
#define C8 (1.0f / 40320.0f)

__device__ __forceinline__ f32x4 ld4(const float* p) { return *reinterpret_cast<const f32x4*>(p); }
__device__ __forceinline__ void st4(float* p, f32x4 v) { *reinterpret_cast<f32x4*>(p) = v; }
__device__ __forceinline__ void tzero(float (&a)[4][4]) {
#pragma unroll
  for (int i = 0; i < 4; ++i)
#pragma unroll
    for (int j = 0; j < 4; ++j) a[i][j] = 0.0f;
}
__device__ __forceinline__ void tfma(float (&a)[4][4], const f32x4 x, const f32x4 y) {
#pragma unroll
  for (int i = 0; i < 4; ++i)
#pragma unroll
    for (int j = 0; j < 4; ++j) a[i][j] = fmaf(x[i], y[j], a[i][j]);
}

// Launch 1: blocks [0,89): powers[b] = expm(k*A) (verified R1/R2 math, unchanged).
// Blocks [89, 89+4096): steps 32x32 tiles (packed-bits compare, verified R2) —
// independent of powers, so they ride along and fill the 167 CUs the prologue
// leaves idle; the whole steps output retires under the expm critical path.
__global__ __launch_bounds__(256, 1) void pre_kernel(const float* __restrict__ U,
                                                     float* __restrict__ powers,
                                                     const int* __restrict__ pw, int L,
                                                     float* __restrict__ out_steps) {
  __shared__ __align__(16) float b0[4096];
  __shared__ __align__(16) float b1[4096];
  __shared__ __align__(16) float b2[4096];
  __shared__ __align__(16) float b3[4096];
  const int t = threadIdx.x;
  const int b = blockIdx.x;

  if (b >= 89) {  // ---- steps tile ----
    const int tb = b - 89;
    const int bi = (tb >> 6) * 32, bj = (tb & 63) * 32;
    unsigned long long* pki = reinterpret_cast<unsigned long long*>(b0);        // 32
    unsigned long long* pkj = pki + 32;                                         // 32
    int* li = reinterpret_cast<int*>(pkj + 32);                                 // 32
    int* lj = li + 32;                                                          // 32
    if (t < 64) {
      const int r = (t < 32) ? (bi + t) : (bj + (t - 32));
      const int* row = pw + (size_t)r * L;
      int len = 0;
      unsigned long long packed = 0ull;
      for (int s = 0; s < L; ++s) {
        const int w = row[s];
        len += (w != PADW) ? 1 : 0;
        packed |= (unsigned long long)(unsigned)(w + 1) << (3 * s);  // w+1 in [0,4]
      }
      if (t < 32) {
        pki[t] = packed;
        li[t] = len;
      } else {
        pkj[t - 32] = packed;
        lj[t - 32] = len;
      }
    }
    __syncthreads();
    const int tx = t & 31, ty0 = t >> 5;
    const unsigned long long xj = pkj[tx];
    const int lenj = lj[tx];
#pragma unroll
    for (int m = 0; m < 4; ++m) {
      const int ty = ty0 + 8 * m;
      const unsigned long long x = pki[ty] ^ xj;
      const int leni = li[ty];
      const int p = x ? (__builtin_ctzll(x) / 3) : L;
      const int common = min(p, min(leni, lenj));
      const float steps = (float)(max(leni, lenj) - common);
      __builtin_nontemporal_store(steps, &out_steps[(size_t)(bi + ty) * NPOS + (bj + tx)]);
    }
    return;
  }

  // ---- expm block ----
  const bool sos = (b == 88);
  const int kp = sos ? 1 : (b >> 3);
  float* __restrict__ dst = powers + (size_t)b * 4096;

  if (kp == 0) {  // B^0 = I
    for (int i = t; i < 4096; i += 256) dst[i] = ((i >> 6) == (i & 63)) ? 1.0f : 0.0f;
    return;
  }

  const int m = sos ? 16 : (NHEADS + (b & 7));
  const float* __restrict__ Um = U + (size_t)m * 4096;
  const float scale = (float)kp * (1.0f / 256.0f);  // k/4 * 1/64

  const int r0 = ((t >> 4) & 15) << 2;  // tile rows r0..r0+3
  const int c0 = (t & 15) << 2;         // tile cols c0..c0+3

  // ---- P0: Ms = scale * (U - U^T) ----
  {
    f32x4 ur[4], uc[4];
#pragma unroll
    for (int i = 0; i < 4; ++i) ur[i] = ld4(&Um[(r0 + i) * 64 + c0]);
#pragma unroll
    for (int j = 0; j < 4; ++j) uc[j] = ld4(&Um[(c0 + j) * 64 + r0]);
#pragma unroll
    for (int i = 0; i < 4; ++i) {
      f32x4 v;
#pragma unroll
      for (int j = 0; j < 4; ++j) v[j] = scale * (ur[i][j] - uc[j][i]);
      st4(&b0[(r0 + i) * 64 + c0], v);
    }
  }
  __syncthreads();

  // ---- P1: M2 = -(Ms^T Ms) ----
  {
    float a[4][4];
    tzero(a);
#pragma unroll 4
    for (int k = 0; k < 64; ++k) tfma(a, ld4(&b0[k * 64 + r0]), ld4(&b0[k * 64 + c0]));
#pragma unroll
    for (int i = 0; i < 4; ++i) {
      f32x4 v;
#pragma unroll
      for (int j = 0; j < 4; ++j) v[j] = -a[i][j];
      st4(&b1[(r0 + i) * 64 + c0], v);
    }
  }
  __syncthreads();

  // ---- P23 (fused): M3 = -(Ms^T M2), M4 = (M2^T M2) ----
  {
    float a3[4][4], a4[4][4];
    tzero(a3);
    tzero(a4);
#pragma unroll 4
    for (int k = 0; k < 64; ++k) {
      const f32x4 msr = ld4(&b0[k * 64 + r0]);
      const f32x4 m2r = ld4(&b1[k * 64 + r0]);
      const f32x4 m2c = ld4(&b1[k * 64 + c0]);
      tfma(a3, msr, m2c);
      tfma(a4, m2r, m2c);
    }
#pragma unroll
    for (int i = 0; i < 4; ++i) {
      f32x4 v3, v4;
#pragma unroll
      for (int j = 0; j < 4; ++j) {
        v3[j] = -a3[i][j];
        v4[j] = a4[i][j];
      }
      st4(&b2[(r0 + i) * 64 + c0], v3);
      st4(&b3[(r0 + i) * 64 + c0], v4);
    }
  }
  __syncthreads();

  // ---- P4 (dual): E = low(M) + M^4*Q(M); Et = E(-M) = E^T ----
  {
    float aE[4][4], aO[4][4];
    tzero(aE);
    tzero(aO);
#pragma unroll 2
    for (int k = 0; k < 64; ++k) {
      const f32x4 xv = ld4(&b3[k * 64 + r0]);  // M4 row (M4^T = M4)
      const f32x4 msv = ld4(&b0[k * 64 + c0]);
      const f32x4 m2v = ld4(&b1[k * 64 + c0]);
      const f32x4 m3v = ld4(&b2[k * 64 + c0]);
      const f32x4 m4v = ld4(&b3[k * 64 + c0]);
      f32x4 ev, ov, yv, yw;
#pragma unroll
      for (int j = 0; j < 4; ++j) {
        ev[j] = fmaf(C8, m4v[j], C6 * m2v[j]);
        ov[j] = fmaf(C7, m3v[j], C5 * msv[j]);
        yv[j] = ev[j] + ov[j];
        yw[j] = ev[j] - ov[j];
      }
      tfma(aE, xv, yv);
      tfma(aO, xv, yw);
    }
    float eT[4][4], oT[4][4];
#pragma unroll
    for (int i = 0; i < 4; ++i) {
      const f32x4 msr = ld4(&b0[(r0 + i) * 64 + c0]);
      const f32x4 m2r = ld4(&b1[(r0 + i) * 64 + c0]);
      const f32x4 m3r = ld4(&b2[(r0 + i) * 64 + c0]);
      const f32x4 m4r = ld4(&b3[(r0 + i) * 64 + c0]);
#pragma unroll
      for (int j = 0; j < 4; ++j) {
        const float d = (r0 + i == c0 + j) ? 1.0f : 0.0f;
        const float even = d + fmaf(C4, m4r[j], C2 * m2r[j]);
        const float odd = fmaf(C3, m3r[j], C1 * msr[j]);
        eT[i][j] = aE[i][j] + even + odd;
        oT[i][j] = aO[i][j] + even - odd;
      }
    }
    __syncthreads();  // all reads of b0..b3 done
#pragma unroll
    for (int i = 0; i < 4; ++i) {
      f32x4 ve, vo;
#pragma unroll
      for (int j = 0; j < 4; ++j) {
        ve[j] = eT[i][j];
        vo[j] = oT[i][j];
      }
      st4(&b0[(r0 + i) * 64 + c0], ve);  // E
      st4(&b1[(r0 + i) * 64 + c0], vo);  // Et
    }
  }
  __syncthreads();

  // ---- P5 (fused): E2 = prim(Et,E); E2t = prim(E,Et) ----
  {
    float aA[4][4], aB[4][4];
    tzero(aA);
    tzero(aB);
#pragma unroll 2
    for (int k = 0; k < 64; ++k) {
      const f32x4 etr = ld4(&b1[k * 64 + r0]);
      const f32x4 er = ld4(&b0[k * 64 + r0]);
      const f32x4 ec = ld4(&b0[k * 64 + c0]);
      const f32x4 etc2 = ld4(&b1[k * 64 + c0]);
      tfma(aA, etr, ec);
      tfma(aB, er, etc2);
    }
#pragma unroll
    for (int i = 0; i < 4; ++i) {
      f32x4 va, vb;
#pragma unroll
      for (int j = 0; j < 4; ++j) {
        va[j] = aA[i][j];
        vb[j] = aB[i][j];
      }
      st4(&b2[(r0 + i) * 64 + c0], va);  // E2
      st4(&b3[(r0 + i) * 64 + c0], vb);  // E2t
    }
  }
  __syncthreads();

  // ---- P6: E4 = prim(E2t,E2) -> global ----
  {
    float a[4][4];
    tzero(a);
#pragma unroll 4
    for (int k = 0; k < 64; ++k) tfma(a, ld4(&b3[k * 64 + r0]), ld4(&b2[k * 64 + c0]));
#pragma unroll
    for (int i = 0; i < 4; ++i) {
      f32x4 v;
#pragma unroll
      for (int j = 0; j < 4; ++j) v[j] = a[i][j];
      st4(&dst[(r0 + i) * 64 + c0], v);
    }
  }
}

// Launch 2: maps only. Each block writes one contiguous 128 KB slab (position n,
// 8 heads) via NONTEMPORAL f32x4 stores — avoids write-allocate/RFO on the
// 268 MB cold output stream. Reads of powers (1.4 MB) stay plain (L2/L3-hot).
__global__ __launch_bounds__(256) void maps_kernel(const float* __restrict__ powers,
                                                   const int* __restrict__ pw, int L,
                                                   float* __restrict__ out_maps) {
  const int t = threadIdx.x;
  const int n = blockIdx.x;
  const int* row = pw + (size_t)n * L;  // wave-uniform -> scalar loads
  const bool sos = (row[0] == -1);
  int c = 0;
  for (int s = 0; s < L; ++s) {
    const int w = row[s];
    c += (w >= 0 && w < 2) ? 1 : 0;
  }
#pragma unroll
  for (int h = 0; h < NHEADS; ++h) {
    const float* src = sos ? (powers + (size_t)88 * 4096)
                           : (powers + (size_t)(c * NHEADS + h) * 4096);
    const f32x4* s4 = reinterpret_cast<const f32x4*>(src);
    f32x4* d4 = reinterpret_cast<f32x4*>(out_maps + ((size_t)n * NHEADS + h) * 4096);
#pragma unroll
    for (int i = 0; i < 4; ++i) {
      const f32x4 v = s4[t + 256 * i];
      __builtin_nontemporal_store(v, &d4[t + 256 * i]);
    }
  }
}

extern "C" void kernel_launch(void* const* d_in, const int* in_sizes, int n_in,
                              void* d_out, int out_size, void* d_ws, size_t ws_size,
                              hipStream_t stream) {
  const float* U = (const float*)d_in[0];
  const int* pw = (const int*)d_in[1];
  const int L = in_sizes[1] / NPOS;  // = 10

  float* powers = (float*)d_ws;  // 89 * 4096 floats: [k*8+h] for k<=10, slot 88 = sos

  float* out_maps = (float*)d_out;
  float* out_steps = out_maps + (size_t)NPOS * NHEADS * 4096;

  hipLaunchKernelGGL(pre_kernel, dim3(89 + 64 * 64), dim3(256), 0, stream, U, powers,
                     pw, L, out_steps);
  hipLaunchKernelGGL(maps_kernel, dim3(NPOS), dim3(256), 0, stream, powers, pw, L,
                     out_maps);
}

// Round 4
// 292.148 us; speedup vs baseline: 1.0350x; 1.0350x over previous
//
#include <hip/hip_runtime.h>

#define DIM 64
#define NHEADS 8
#define NPOS 2048
#define PADW 3

typedef float f32x4 __attribute__((ext_vector_type(4)));

// Taylor coefficients 1/j!
#define C1 1.0f
#define C2 0.5f
#define C3 (1.0f / 6.0f)
#define C4 (1.0f / 24.0f)
#define C5 (1.0f / 120.0f)
#define C6 (1.0f / 720.0f)
#define C7 (1.0f / 5040.0f)
#define C8 (1.0f / 40320.0f)

__device__ __forceinline__ f32x4 ld4(const float* p) { return *reinterpret_cast<const f32x4*>(p); }
__device__ __forceinline__ void st4(float* p, f32x4 v) { *reinterpret_cast<f32x4*>(p) = v; }
__device__ __forceinline__ void tzero(float (&a)[4][4]) {
#pragma unroll
  for (int i = 0; i < 4; ++i)
#pragma unroll
    for (int j = 0; j < 4; ++j) a[i][j] = 0.0f;
}
__device__ __forceinline__ void tfma(float (&a)[4][4], const f32x4 x, const f32x4 y) {
#pragma unroll
  for (int i = 0; i < 4; ++i)
#pragma unroll
    for (int j = 0; j < 4; ++j) a[i][j] = fmaf(x[i], y[j], a[i][j]);
}

// Launch 1: blocks [0,89): powers[b] = expm(k*A) (verified R1-R3 math, unchanged).
// Blocks [89, 89+4096): steps 32x32 tiles (packed-bits compare, verified R2/R3).
// Steps blocks inherit the 64 KB static LDS (2 blocks/CU) but ~420 run
// concurrently on the CUs the 89 expm blocks leave idle -> they retire under the
// expm critical path (~22 us of ds-pipe issue).
__global__ __launch_bounds__(256, 1) void pre_kernel(const float* __restrict__ U,
                                                     float* __restrict__ powers,
                                                     const int* __restrict__ pw, int L,
                                                     float* __restrict__ out_steps) {
  __shared__ __align__(16) float b0[4096];
  __shared__ __align__(16) float b1[4096];
  __shared__ __align__(16) float b2[4096];
  __shared__ __align__(16) float b3[4096];
  const int t = threadIdx.x;
  const int b = blockIdx.x;

  if (b >= 89) {  // ---- steps tile ----
    const int tb = b - 89;
    const int bi = (tb >> 6) * 32, bj = (tb & 63) * 32;
    unsigned long long* pki = reinterpret_cast<unsigned long long*>(b0);  // 32
    unsigned long long* pkj = pki + 32;                                   // 32
    int* li = reinterpret_cast<int*>(pkj + 32);                           // 32
    int* lj = li + 32;                                                    // 32
    if (t < 64) {
      const int r = (t < 32) ? (bi + t) : (bj + (t - 32));
      const int* row = pw + (size_t)r * L;
      int len = 0;
      unsigned long long packed = 0ull;
      for (int s = 0; s < L; ++s) {
        const int w = row[s];
        len += (w != PADW) ? 1 : 0;
        packed |= (unsigned long long)(unsigned)(w + 1) << (3 * s);  // w+1 in [0,4]
      }
      if (t < 32) {
        pki[t] = packed;
        li[t] = len;
      } else {
        pkj[t - 32] = packed;
        lj[t - 32] = len;
      }
    }
    __syncthreads();
    const int tx = t & 31, ty0 = t >> 5;
    const unsigned long long xj = pkj[tx];
    const int lenj = lj[tx];
#pragma unroll
    for (int m = 0; m < 4; ++m) {
      const int ty = ty0 + 8 * m;
      const unsigned long long x = pki[ty] ^ xj;
      const int leni = li[ty];
      const int p = x ? (__builtin_ctzll(x) / 3) : L;
      const int common = min(p, min(leni, lenj));
      const float steps = (float)(max(leni, lenj) - common);
      out_steps[(size_t)(bi + ty) * NPOS + (bj + tx)] = steps;
    }
    return;
  }

  // ---- expm block ----
  const bool sos = (b == 88);
  const int kp = sos ? 1 : (b >> 3);
  float* __restrict__ dst = powers + (size_t)b * 4096;

  if (kp == 0) {  // B^0 = I
    for (int i = t; i < 4096; i += 256) dst[i] = ((i >> 6) == (i & 63)) ? 1.0f : 0.0f;
    return;
  }

  const int m = sos ? 16 : (NHEADS + (b & 7));
  const float* __restrict__ Um = U + (size_t)m * 4096;
  const float scale = (float)kp * (1.0f / 256.0f);  // k/4 * 1/64

  const int r0 = ((t >> 4) & 15) << 2;  // tile rows r0..r0+3
  const int c0 = (t & 15) << 2;         // tile cols c0..c0+3

  // ---- P0: Ms = scale * (U - U^T) ----
  {
    f32x4 ur[4], uc[4];
#pragma unroll
    for (int i = 0; i < 4; ++i) ur[i] = ld4(&Um[(r0 + i) * 64 + c0]);
#pragma unroll
    for (int j = 0; j < 4; ++j) uc[j] = ld4(&Um[(c0 + j) * 64 + r0]);
#pragma unroll
    for (int i = 0; i < 4; ++i) {
      f32x4 v;
#pragma unroll
      for (int j = 0; j < 4; ++j) v[j] = scale * (ur[i][j] - uc[j][i]);
      st4(&b0[(r0 + i) * 64 + c0], v);
    }
  }
  __syncthreads();

  // ---- P1: M2 = -(Ms^T Ms) ----
  {
    float a[4][4];
    tzero(a);
#pragma unroll 4
    for (int k = 0; k < 64; ++k) tfma(a, ld4(&b0[k * 64 + r0]), ld4(&b0[k * 64 + c0]));
#pragma unroll
    for (int i = 0; i < 4; ++i) {
      f32x4 v;
#pragma unroll
      for (int j = 0; j < 4; ++j) v[j] = -a[i][j];
      st4(&b1[(r0 + i) * 64 + c0], v);
    }
  }
  __syncthreads();

  // ---- P23 (fused): M3 = -(Ms^T M2), M4 = (M2^T M2) ----
  {
    float a3[4][4], a4[4][4];
    tzero(a3);
    tzero(a4);
#pragma unroll 4
    for (int k = 0; k < 64; ++k) {
      const f32x4 msr = ld4(&b0[k * 64 + r0]);
      const f32x4 m2r = ld4(&b1[k * 64 + r0]);
      const f32x4 m2c = ld4(&b1[k * 64 + c0]);
      tfma(a3, msr, m2c);
      tfma(a4, m2r, m2c);
    }
#pragma unroll
    for (int i = 0; i < 4; ++i) {
      f32x4 v3, v4;
#pragma unroll
      for (int j = 0; j < 4; ++j) {
        v3[j] = -a3[i][j];
        v4[j] = a4[i][j];
      }
      st4(&b2[(r0 + i) * 64 + c0], v3);
      st4(&b3[(r0 + i) * 64 + c0], v4);
    }
  }
  __syncthreads();

  // ---- P4 (dual): E = low(M) + M^4*Q(M); Et = E(-M) = E^T ----
  {
    float aE[4][4], aO[4][4];
    tzero(aE);
    tzero(aO);
#pragma unroll 2
    for (int k = 0; k < 64; ++k) {
      const f32x4 xv = ld4(&b3[k * 64 + r0]);  // M4 row (M4^T = M4)
      const f32x4 msv = ld4(&b0[k * 64 + c0]);
      const f32x4 m2v = ld4(&b1[k * 64 + c0]);
      const f32x4 m3v = ld4(&b2[k * 64 + c0]);
      const f32x4 m4v = ld4(&b3[k * 64 + c0]);
      f32x4 ev, ov, yv, yw;
#pragma unroll
      for (int j = 0; j < 4; ++j) {
        ev[j] = fmaf(C8, m4v[j], C6 * m2v[j]);
        ov[j] = fmaf(C7, m3v[j], C5 * msv[j]);
        yv[j] = ev[j] + ov[j];
        yw[j] = ev[j] - ov[j];
      }
      tfma(aE, xv, yv);
      tfma(aO, xv, yw);
    }
    float eT[4][4], oT[4][4];
#pragma unroll
    for (int i = 0; i < 4; ++i) {
      const f32x4 msr = ld4(&b0[(r0 + i) * 64 + c0]);
      const f32x4 m2r = ld4(&b1[(r0 + i) * 64 + c0]);
      const f32x4 m3r = ld4(&b2[(r0 + i) * 64 + c0]);
      const f32x4 m4r = ld4(&b3[(r0 + i) * 64 + c0]);
#pragma unroll
      for (int j = 0; j < 4; ++j) {
        const float d = (r0 + i == c0 + j) ? 1.0f : 0.0f;
        const float even = d + fmaf(C4, m4r[j], C2 * m2r[j]);
        const float odd = fmaf(C3, m3r[j], C1 * msr[j]);
        eT[i][j] = aE[i][j] + even + odd;
        oT[i][j] = aO[i][j] + even - odd;
      }
    }
    __syncthreads();  // all reads of b0..b3 done
#pragma unroll
    for (int i = 0; i < 4; ++i) {
      f32x4 ve, vo;
#pragma unroll
      for (int j = 0; j < 4; ++j) {
        ve[j] = eT[i][j];
        vo[j] = oT[i][j];
      }
      st4(&b0[(r0 + i) * 64 + c0], ve);  // E
      st4(&b1[(r0 + i) * 64 + c0], vo);  // Et
    }
  }
  __syncthreads();

  // ---- P5 (fused): E2 = prim(Et,E); E2t = prim(E,Et) ----
  {
    float aA[4][4], aB[4][4];
    tzero(aA);
    tzero(aB);
#pragma unroll 2
    for (int k = 0; k < 64; ++k) {
      const f32x4 etr = ld4(&b1[k * 64 + r0]);
      const f32x4 er = ld4(&b0[k * 64 + r0]);
      const f32x4 ec = ld4(&b0[k * 64 + c0]);
      const f32x4 etc2 = ld4(&b1[k * 64 + c0]);
      tfma(aA, etr, ec);
      tfma(aB, er, etc2);
    }
#pragma unroll
    for (int i = 0; i < 4; ++i) {
      f32x4 va, vb;
#pragma unroll
      for (int j = 0; j < 4; ++j) {
        va[j] = aA[i][j];
        vb[j] = aB[i][j];
      }
      st4(&b2[(r0 + i) * 64 + c0], va);  // E2
      st4(&b3[(r0 + i) * 64 + c0], vb);  // E2t
    }
  }
  __syncthreads();

  // ---- P6: E4 = prim(E2t,E2) -> global ----
  {
    float a[4][4];
    tzero(a);
#pragma unroll 4
    for (int k = 0; k < 64; ++k) tfma(a, ld4(&b3[k * 64 + r0]), ld4(&b2[k * 64 + c0]));
#pragma unroll
    for (int i = 0; i < 4; ++i) {
      f32x4 v;
#pragma unroll
      for (int j = 0; j < 4; ++j) v[j] = a[i][j];
      st4(&dst[(r0 + i) * 64 + c0], v);
    }
  }
}

// Launch 2: maps only, PER-HEAD blocks (16384 x 16 KB). 8 consecutive blocks
// cover one position's contiguous 128 KB. PLAIN f32x4 stores (NT measured
// neutral-to-negative R2/R3; full coalesced lines don't RFO on this L2).
// powers reads (<=256 KB hot set) stay cached.
__global__ __launch_bounds__(256) void maps_kernel(const float* __restrict__ powers,
                                                   const int* __restrict__ pw, int L,
                                                   float* __restrict__ out_maps) {
  const int t = threadIdx.x;
  const int n = blockIdx.x >> 3;
  const int h = blockIdx.x & 7;
  const int* row = pw + (size_t)n * L;  // wave-uniform -> scalar loads
  const bool sos = (row[0] == -1);
  int c = 0;
  for (int s = 0; s < L; ++s) {
    const int w = row[s];
    c += (w >= 0 && w < 2) ? 1 : 0;
  }
  const float* src = sos ? (powers + (size_t)88 * 4096)
                         : (powers + (size_t)(c * NHEADS + h) * 4096);
  const f32x4* s4 = reinterpret_cast<const f32x4*>(src);
  f32x4* d4 = reinterpret_cast<f32x4*>(out_maps + ((size_t)n * NHEADS + h) * 4096);
  f32x4 v0 = s4[t];
  f32x4 v1 = s4[t + 256];
  f32x4 v2 = s4[t + 512];
  f32x4 v3 = s4[t + 768];
  d4[t] = v0;
  d4[t + 256] = v1;
  d4[t + 512] = v2;
  d4[t + 768] = v3;
}

extern "C" void kernel_launch(void* const* d_in, const int* in_sizes, int n_in,
                              void* d_out, int out_size, void* d_ws, size_t ws_size,
                              hipStream_t stream) {
  const float* U = (const float*)d_in[0];
  const int* pw = (const int*)d_in[1];
  const int L = in_sizes[1] / NPOS;  // = 10

  float* powers = (float*)d_ws;  // 89 * 4096 floats: [k*8+h] for k<=10, slot 88 = sos

  float* out_maps = (float*)d_out;
  float* out_steps = out_maps + (size_t)NPOS * NHEADS * 4096;

  hipLaunchKernelGGL(pre_kernel, dim3(89 + 64 * 64), dim3(256), 0, stream, U, powers,
                     pw, L, out_steps);
  hipLaunchKernelGGL(maps_kernel, dim3(NPOS * NHEADS), dim3(256), 0, stream, powers,
                     pw, L, out_maps);
}